// Round 3
// baseline (3290.209 us; speedup 1.0000x reference)
//
#include <hip/hip_runtime.h>
#include <math.h>

typedef __attribute__((ext_vector_type(4))) float f32x4;

#define NPTS   131072
#define TBL    32768
#define MT     32
#define TWO_PI 6.28318530717958647692f

// Pure fp32 VALU implementation — direct transcription of the numpy reference.
// Diagnostic bisect: no MFMA, no bf16, no workspace, no device globals.
__global__ __launch_bounds__(256, 2) void ffb_fp32(
    const float* __restrict__ in_pos, const float* __restrict__ table,
    const float* __restrict__ ffnA, const float* __restrict__ W0,
    const float* __restrict__ b0, const float* __restrict__ Ws,
    const float* __restrict__ bs, const float* __restrict__ Wh,
    const float* __restrict__ bh, float* __restrict__ out)
{
    __shared__ __align__(16) float xbuf[MT][260];   // row stride 260: 16B-aligned rows
    __shared__ __align__(16) float gf[4][MT][8];
    __shared__ float ptile[MT][3];

    const int t  = threadIdx.x;                      // t = output column n, 0..255
    const int m0 = blockIdx.x * MT;

    if (t < MT * 3) ((float*)ptile)[t] = in_pos[m0 * 3 + t];
    __syncthreads();

    // ---- hash-grid encode: threads 0..127 -> (level l = t>>5, point m = t&31)
    if (t < 128) {
        const int l = t >> 5, m = t & 31;
        const float px = ptile[m][0], py = ptile[m][1], pz = ptile[m][2];
        const float res = (float)(16 << l);
        const float fx = (px + 1.0f) * 0.5f * res;
        const float fy = (py + 1.0f) * 0.5f * res;
        const float fz = (pz + 1.0f) * 0.5f * res;
        const float f0x = floorf(fx), f0y = floorf(fy), f0z = floorf(fz);
        const float frx = fx - f0x, fry = fy - f0y, frz = fz - f0z;
        const unsigned ux = (unsigned)f0x, uy = (unsigned)f0y, uz = (unsigned)f0z;
        float acc[8];
#pragma unroll
        for (int f = 0; f < 8; ++f) acc[f] = 0.0f;
#pragma unroll
        for (int c = 0; c < 8; ++c) {
            const unsigned cx = ux + ((c >> 2) & 1);
            const unsigned cy = uy + ((c >> 1) & 1);
            const unsigned cz = uz + (c & 1);
            const unsigned id = (cx * 1u ^ cy * 2654435761u ^ cz * 805459861u) & (TBL - 1);
            const float4* tp = (const float4*)(table + ((size_t)(l * TBL + id) << 3));
            const float4 t0 = tp[0], t1 = tp[1];
            const float wx = (c & 4) ? frx : 1.0f - frx;
            const float wy = (c & 2) ? fry : 1.0f - fry;
            const float wz = (c & 1) ? frz : 1.0f - frz;
            const float w = wx * wy * wz;
            acc[0] += w * t0.x; acc[1] += w * t0.y; acc[2] += w * t0.z; acc[3] += w * t0.w;
            acc[4] += w * t1.x; acc[5] += w * t1.y; acc[6] += w * t1.z; acc[7] += w * t1.w;
        }
#pragma unroll
        for (int f = 0; f < 8; ++f) gf[l][m][f] = acc[f];
    }

    // ---- layer 0: xbuf[m][t] = sin(pos[m] . W0[:,t] + b0[t])
    {
        const float w0 = W0[t], w1 = W0[256 + t], w2 = W0[512 + t], bb = b0[t];
#pragma unroll
        for (int m = 0; m < MT; ++m)
            xbuf[m][t] = sinf(ptile[m][0] * w0 + ptile[m][1] * w1 + ptile[m][2] * w2 + bb);
    }
    __syncthreads();

    float xout[MT];
#pragma unroll
    for (int m = 0; m < MT; ++m) xout[m] = 0.0f;

    for (int l = 0; l < 4; ++l) {
        // ===== GEMM1: acc[m] = sum_k xbuf[m][k] * Ws[l][k][t] =====
        float acc[MT];
#pragma unroll
        for (int m = 0; m < MT; ++m) acc[m] = 0.0f;
        for (int kt = 0; kt < 8; ++kt) {
            float w[32];
#pragma unroll
            for (int kk = 0; kk < 32; ++kk)
                w[kk] = Ws[(size_t)(((l << 8) + kt * 32 + kk) << 8) + t];
#pragma unroll
            for (int m = 0; m < MT; ++m) {
                const f32x4* xr = (const f32x4*)&xbuf[m][kt * 32];
                float s = acc[m];
#pragma unroll
                for (int q = 0; q < 8; ++q) {
                    const f32x4 xv = xr[q];
                    s += xv.x * w[q * 4 + 0];
                    s += xv.y * w[q * 4 + 1];
                    s += xv.z * w[q * 4 + 2];
                    s += xv.w * w[q * 4 + 3];
                }
                acc[m] = s;
            }
        }
        __syncthreads();   // all threads done reading xbuf

        // ---- epilogue 1: xbuf[m][t] = sin(acc+bs) + sin(2pi * gf[l][m].A[l][:,t]*2^l)
        {
            float at[8];
#pragma unroll
            for (int f = 0; f < 8; ++f)
                at[f] = ffnA[(l << 11) + (f << 8) + t] * (float)(1 << l);
            const float bsv = bs[(l << 8) + t];
#pragma unroll
            for (int m = 0; m < MT; ++m) {
                const f32x4 g0 = *(const f32x4*)&gf[l][m][0];
                const f32x4 g1 = *(const f32x4*)&gf[l][m][4];
                const float g = g0.x * at[0] + g0.y * at[1] + g0.z * at[2] + g0.w * at[3]
                              + g1.x * at[4] + g1.y * at[5] + g1.z * at[6] + g1.w * at[7];
                xbuf[m][t] = sinf(acc[m] + bsv) + sinf(TWO_PI * g);
            }
        }
        __syncthreads();   // xbuf update visible

        // ===== GEMM2: acc2[m] = sum_k xbuf[m][k] * Wh[l][k][t] =====
        float acc2[MT];
#pragma unroll
        for (int m = 0; m < MT; ++m) acc2[m] = 0.0f;
        for (int kt = 0; kt < 8; ++kt) {
            float w[32];
#pragma unroll
            for (int kk = 0; kk < 32; ++kk)
                w[kk] = Wh[(size_t)(((l << 8) + kt * 32 + kk) << 8) + t];
#pragma unroll
            for (int m = 0; m < MT; ++m) {
                const f32x4* xr = (const f32x4*)&xbuf[m][kt * 32];
                float s = acc2[m];
#pragma unroll
                for (int q = 0; q < 8; ++q) {
                    const f32x4 xv = xr[q];
                    s += xv.x * w[q * 4 + 0];
                    s += xv.y * w[q * 4 + 1];
                    s += xv.z * w[q * 4 + 2];
                    s += xv.w * w[q * 4 + 3];
                }
                acc2[m] = s;
            }
        }
        // no barrier: next xbuf write is after next layer's post-GEMM1 barrier

        // ---- epilogue 2: x_out += sin(acc2 + bh)
        {
            const float bhv = bh[(l << 8) + t];
#pragma unroll
            for (int m = 0; m < MT; ++m) xout[m] += sinf(acc2[m] + bhv);
        }
    }

    // ---- store
#pragma unroll
    for (int m = 0; m < MT; ++m)
        out[(size_t)(m0 + m) * 256 + t] = xout[m];
}

// ---------------- launch ---------------------------------------------------
extern "C" void kernel_launch(void* const* d_in, const int* in_sizes, int n_in,
                              void* d_out, int out_size, void* d_ws, size_t ws_size,
                              hipStream_t stream) {
    const float* in_pos = (const float*)d_in[0];
    const float* table  = (const float*)d_in[1];
    const float* ffn_A  = (const float*)d_in[2];
    const float* W0     = (const float*)d_in[3];
    const float* b0     = (const float*)d_in[4];
    const float* Ws     = (const float*)d_in[5];
    const float* bs     = (const float*)d_in[6];
    const float* Wh     = (const float*)d_in[7];
    const float* bh     = (const float*)d_in[8];
    float* out = (float*)d_out;

    ffb_fp32<<<NPTS / MT, 256, 0, stream>>>(in_pos, table, ffn_A, W0, b0,
                                            Ws, bs, Wh, bh, out);
}

// Round 5
// 1441.990 us; speedup vs baseline: 2.2817x; 2.2817x over previous
//
#include <hip/hip_runtime.h>
#include <hip/hip_bf16.h>
#include <math.h>

typedef __attribute__((ext_vector_type(8))) __bf16 bf16x8;
typedef __attribute__((ext_vector_type(4))) float f32x4;

#define NPTS   131072
#define TBL    32768
#define MT     32
#define TWO_PI 6.28318530717958647692f

// R5: MFMA GEMMs on the R3-proven scaffold. No prep kernel, no transpose,
// no device globals: weights read fp32 from original layout, split to
// bf16 hi/lo in registers, 3-term MFMA (hh + lh + hl; ll term ~2^-18, dropped).
__global__ __launch_bounds__(256, 2) void ffb_main(
    const float* __restrict__ in_pos, const float* __restrict__ table,
    const float* __restrict__ ffnA, const float* __restrict__ W0,
    const float* __restrict__ b0, const float* __restrict__ Ws,
    const float* __restrict__ bs, const float* __restrict__ Wh,
    const float* __restrict__ bh, float* __restrict__ out)
{
    __shared__ __align__(16) float xbuf[MT][260];   // fp32 x tile (R3-proven)
    __shared__ __align__(16) float gf[4][MT][8];
    __shared__ float ptile[MT][3];

    const int tid   = threadIdx.x;
    const int wave  = tid >> 6;
    const int lane  = tid & 63;
    const int laneN = lane & 15;      // A row m / B col n / D col
    const int kb    = lane >> 4;      // k-octet / D row-quad
    const int m0    = blockIdx.x * MT;

    if (tid < MT * 3) ((float*)ptile)[tid] = in_pos[m0 * 3 + tid];
    __syncthreads();

    // ---- hash-grid encode (R3 verbatim)
    if (tid < 128) {
        const int l = tid >> 5, m = tid & 31;
        const float px = ptile[m][0], py = ptile[m][1], pz = ptile[m][2];
        const float res = (float)(16 << l);
        const float fx = (px + 1.0f) * 0.5f * res;
        const float fy = (py + 1.0f) * 0.5f * res;
        const float fz = (pz + 1.0f) * 0.5f * res;
        const float f0x = floorf(fx), f0y = floorf(fy), f0z = floorf(fz);
        const float frx = fx - f0x, fry = fy - f0y, frz = fz - f0z;
        const unsigned ux = (unsigned)f0x, uy = (unsigned)f0y, uz = (unsigned)f0z;
        float acc[8];
#pragma unroll
        for (int f = 0; f < 8; ++f) acc[f] = 0.0f;
#pragma unroll
        for (int c = 0; c < 8; ++c) {
            const unsigned cx = ux + ((c >> 2) & 1);
            const unsigned cy = uy + ((c >> 1) & 1);
            const unsigned cz = uz + (c & 1);
            const unsigned id = (cx * 1u ^ cy * 2654435761u ^ cz * 805459861u) & (TBL - 1);
            const float4* tp = (const float4*)(table + ((size_t)(l * TBL + id) << 3));
            const float4 t0 = tp[0], t1 = tp[1];
            const float wx = (c & 4) ? frx : 1.0f - frx;
            const float wy = (c & 2) ? fry : 1.0f - fry;
            const float wz = (c & 1) ? frz : 1.0f - frz;
            const float w = wx * wy * wz;
            acc[0] += w * t0.x; acc[1] += w * t0.y; acc[2] += w * t0.z; acc[3] += w * t0.w;
            acc[4] += w * t1.x; acc[5] += w * t1.y; acc[6] += w * t1.z; acc[7] += w * t1.w;
        }
#pragma unroll
        for (int f = 0; f < 8; ++f) gf[l][m][f] = acc[f];
    }

    // ---- layer 0 (R3 verbatim)
    {
        const float w0 = W0[tid], w1 = W0[256 + tid], w2 = W0[512 + tid], bb = b0[tid];
#pragma unroll
        for (int m = 0; m < MT; ++m)
            xbuf[m][tid] = sinf(ptile[m][0] * w0 + ptile[m][1] * w1 + ptile[m][2] * w2 + bb);
    }
    __syncthreads();

    f32x4 xout[2][4];
#pragma unroll
    for (int mt = 0; mt < 2; ++mt)
#pragma unroll
        for (int nt = 0; nt < 4; ++nt) xout[mt][nt] = (f32x4)0.0f;

    for (int l = 0; l < 4; ++l) {
        // ===== GEMM1: z1 = X @ Ws[l], split-bf16 MFMA, W from original layout
        f32x4 acc[2][4];
#pragma unroll
        for (int mt = 0; mt < 2; ++mt)
#pragma unroll
            for (int nt = 0; nt < 4; ++nt) acc[mt][nt] = (f32x4)0.0f;

        for (int kt = 0; kt < 8; ++kt) {
            const int k0 = kt * 32 + kb * 8;
            bf16x8 ah[2], al[2], wh8[4], wl8[4];
#pragma unroll
            for (int mt = 0; mt < 2; ++mt) {
                const f32x4 v0 = *(const f32x4*)&xbuf[mt * 16 + laneN][k0];
                const f32x4 v1 = *(const f32x4*)&xbuf[mt * 16 + laneN][k0 + 4];
                const float tmp[8] = {v0.x, v0.y, v0.z, v0.w, v1.x, v1.y, v1.z, v1.w};
#pragma unroll
                for (int j = 0; j < 8; ++j) {
                    const float v = tmp[j];
                    const __bf16 h = (__bf16)v;
                    ah[mt][j] = h;
                    al[mt][j] = (__bf16)(v - (float)h);
                }
            }
            const float* Bbase = Ws + ((size_t)((l << 8) + k0) << 8);
#pragma unroll
            for (int nt = 0; nt < 4; ++nt) {
                const int ncol = wave * 64 + nt * 16 + laneN;
#pragma unroll
                for (int j = 0; j < 8; ++j) {
                    const float w = Bbase[(j << 8) + ncol];   // Ws[l][k0+j][ncol]
                    const __bf16 h = (__bf16)w;
                    wh8[nt][j] = h;
                    wl8[nt][j] = (__bf16)(w - (float)h);
                }
            }
#pragma unroll
            for (int mt = 0; mt < 2; ++mt)
#pragma unroll
                for (int nt = 0; nt < 4; ++nt) {
                    acc[mt][nt] = __builtin_amdgcn_mfma_f32_16x16x32_bf16(al[mt], wh8[nt], acc[mt][nt], 0, 0, 0);
                    acc[mt][nt] = __builtin_amdgcn_mfma_f32_16x16x32_bf16(ah[mt], wl8[nt], acc[mt][nt], 0, 0, 0);
                    acc[mt][nt] = __builtin_amdgcn_mfma_f32_16x16x32_bf16(ah[mt], wh8[nt], acc[mt][nt], 0, 0, 0);
                }
        }
        __syncthreads();   // all waves done reading xbuf (x_{l-1} dead after this)

        // ---- scatter z1 into xbuf via believed C/D layout
#pragma unroll
        for (int mt = 0; mt < 2; ++mt)
#pragma unroll
            for (int r = 0; r < 4; ++r) {
                const int m = mt * 16 + kb * 4 + r;
#pragma unroll
                for (int nt = 0; nt < 4; ++nt)
                    xbuf[m][wave * 64 + nt * 16 + laneN] = acc[mt][nt][r];
            }
        __syncthreads();

        // ---- epilogue 1 (R3 verbatim, thread-per-column, in-place)
        {
            float at[8];
#pragma unroll
            for (int f = 0; f < 8; ++f)
                at[f] = ffnA[(l << 11) + (f << 8) + tid] * (float)(1 << l);
            const float bsv = bs[(l << 8) + tid];
#pragma unroll
            for (int m = 0; m < MT; ++m) {
                const f32x4 g0 = *(const f32x4*)&gf[l][m][0];
                const f32x4 g1 = *(const f32x4*)&gf[l][m][4];
                const float g = g0.x * at[0] + g0.y * at[1] + g0.z * at[2] + g0.w * at[3]
                              + g1.x * at[4] + g1.y * at[5] + g1.z * at[6] + g1.w * at[7];
                xbuf[m][tid] = sinf(xbuf[m][tid] + bsv) + sinf(TWO_PI * g);
            }
        }
        __syncthreads();   // x_l visible to all waves

        // ===== GEMM2: z2 = X @ Wh[l] =====
        f32x4 acc2[2][4];
#pragma unroll
        for (int mt = 0; mt < 2; ++mt)
#pragma unroll
            for (int nt = 0; nt < 4; ++nt) acc2[mt][nt] = (f32x4)0.0f;

        for (int kt = 0; kt < 8; ++kt) {
            const int k0 = kt * 32 + kb * 8;
            bf16x8 ah[2], al[2], wh8[4], wl8[4];
#pragma unroll
            for (int mt = 0; mt < 2; ++mt) {
                const f32x4 v0 = *(const f32x4*)&xbuf[mt * 16 + laneN][k0];
                const f32x4 v1 = *(const f32x4*)&xbuf[mt * 16 + laneN][k0 + 4];
                const float tmp[8] = {v0.x, v0.y, v0.z, v0.w, v1.x, v1.y, v1.z, v1.w};
#pragma unroll
                for (int j = 0; j < 8; ++j) {
                    const float v = tmp[j];
                    const __bf16 h = (__bf16)v;
                    ah[mt][j] = h;
                    al[mt][j] = (__bf16)(v - (float)h);
                }
            }
            const float* Bbase = Wh + ((size_t)((l << 8) + k0) << 8);
#pragma unroll
            for (int nt = 0; nt < 4; ++nt) {
                const int ncol = wave * 64 + nt * 16 + laneN;
#pragma unroll
                for (int j = 0; j < 8; ++j) {
                    const float w = Bbase[(j << 8) + ncol];   // Wh[l][k0+j][ncol]
                    const __bf16 h = (__bf16)w;
                    wh8[nt][j] = h;
                    wl8[nt][j] = (__bf16)(w - (float)h);
                }
            }
#pragma unroll
            for (int mt = 0; mt < 2; ++mt)
#pragma unroll
                for (int nt = 0; nt < 4; ++nt) {
                    acc2[mt][nt] = __builtin_amdgcn_mfma_f32_16x16x32_bf16(al[mt], wh8[nt], acc2[mt][nt], 0, 0, 0);
                    acc2[mt][nt] = __builtin_amdgcn_mfma_f32_16x16x32_bf16(ah[mt], wl8[nt], acc2[mt][nt], 0, 0, 0);
                    acc2[mt][nt] = __builtin_amdgcn_mfma_f32_16x16x32_bf16(ah[mt], wh8[nt], acc2[mt][nt], 0, 0, 0);
                }
        }
        // z2 stays in registers; x_l stays in xbuf for next layer's GEMM1.

        // ---- epilogue 2 (elementwise, C-layout registers)
#pragma unroll
        for (int nt = 0; nt < 4; ++nt) {
            const float bhv = bh[(l << 8) + wave * 64 + nt * 16 + laneN];
#pragma unroll
            for (int mt = 0; mt < 2; ++mt)
#pragma unroll
                for (int r = 0; r < 4; ++r)
                    xout[mt][nt][r] += sinf(acc2[mt][nt][r] + bhv);
        }
    }

    // ---- store (C/D layout)
#pragma unroll
    for (int mt = 0; mt < 2; ++mt)
#pragma unroll
        for (int r = 0; r < 4; ++r) {
            const int m = mt * 16 + kb * 4 + r;
#pragma unroll
            for (int nt = 0; nt < 4; ++nt)
                out[(size_t)(m0 + m) * 256 + wave * 64 + nt * 16 + laneN] = xout[mt][nt][r];
        }
}

// ---------------- launch ---------------------------------------------------
extern "C" void kernel_launch(void* const* d_in, const int* in_sizes, int n_in,
                              void* d_out, int out_size, void* d_ws, size_t ws_size,
                              hipStream_t stream) {
    const float* in_pos = (const float*)d_in[0];
    const float* table  = (const float*)d_in[1];
    const float* ffn_A  = (const float*)d_in[2];
    const float* W0     = (const float*)d_in[3];
    const float* b0     = (const float*)d_in[4];
    const float* Ws     = (const float*)d_in[5];
    const float* bs     = (const float*)d_in[6];
    const float* Wh     = (const float*)d_in[7];
    const float* bh     = (const float*)d_in[8];
    float* out = (float*)d_out;

    ffb_main<<<NPTS / MT, 256, 0, stream>>>(in_pos, table, ffn_A, W0, b0,
                                            Ws, bs, Wh, bh, out);
}